// Round 2
// baseline (17673.956 us; speedup 1.0000x reference)
//
#include <hip/hip_runtime.h>
#include <hip/hip_bf16.h>
#include <math.h>

#define BQ 128   // batch
#define TT 20    // timesteps
#define RR 49    // regions
#define DD 2048  // feature dim
#define EE 512   // embed dim
#define HH 512   // hidden
#define VV 10000 // vocab
constexpr float EPSV = 1e-5f;

__device__ __forceinline__ float sigmoidf(float x) { return 1.f / (1.f + expf(-x)); }

// mean over R regions: features [B,R,D] -> mean_f [B,D]
__global__ void mean_kernel(const float* __restrict__ features, float* __restrict__ mean_f) {
  int idx = blockIdx.x * blockDim.x + threadIdx.x;
  if (idx >= BQ * DD) return;
  int b = idx / DD, d = idx - b * DD;
  const float* p = features + (long)b * RR * DD + d;
  float s = 0.f;
  for (int r = 0; r < RR; ++r) s += p[(long)r * DD];
  mean_f[idx] = s * (1.f / RR);
}

// C[M,N] = A[M,K] @ W[N,K]^T (+bias) (+beta*C) (+relu). fp32.
// K must be a multiple of 16. A row-major lda=K. C row stride = ldc.
__global__ void gemm_tn(const float* __restrict__ A, const float* __restrict__ W,
                        const float* __restrict__ bias, float* __restrict__ C,
                        int M, int N, int K, long ldc, int beta, int act) {
  __shared__ float As[16][65];
  __shared__ float Bs[16][65];
  int tid = threadIdx.x;
  int bm = blockIdx.y * 64, bn = blockIdx.x * 64;
  int tx = tid & 15, ty = tid >> 4;
  float acc[4][4] = {};
  for (int k0 = 0; k0 < K; k0 += 16) {
    for (int i = tid; i < 64 * 16; i += 256) {
      int m = i >> 4, kk = i & 15;
      int gm = bm + m, gk = k0 + kk;
      As[kk][m] = (gm < M) ? A[(long)gm * K + gk] : 0.f;
    }
    for (int i = tid; i < 64 * 16; i += 256) {
      int n = i >> 4, kk = i & 15;
      int gn = bn + n, gk = k0 + kk;
      Bs[kk][n] = (gn < N) ? W[(long)gn * K + gk] : 0.f;
    }
    __syncthreads();
#pragma unroll
    for (int kk = 0; kk < 16; ++kk) {
      float a[4], b[4];
#pragma unroll
      for (int i = 0; i < 4; ++i) a[i] = As[kk][ty * 4 + i];
#pragma unroll
      for (int j = 0; j < 4; ++j) b[j] = Bs[kk][tx * 4 + j];
#pragma unroll
      for (int i = 0; i < 4; ++i)
#pragma unroll
        for (int j = 0; j < 4; ++j) acc[i][j] += a[i] * b[j];
    }
    __syncthreads();
  }
#pragma unroll
  for (int i = 0; i < 4; ++i) {
    int gm = bm + ty * 4 + i;
    if (gm >= M) continue;
#pragma unroll
    for (int j = 0; j < 4; ++j) {
      int gn = bn + tx * 4 + j;
      if (gn >= N) continue;
      float v = acc[i][j];
      if (bias) v += bias[gn];
      if (beta) v += C[(long)gm * ldc + gn];
      if (act) v = fmaxf(v, 0.f);
      C[(long)gm * ldc + gn] = v;
    }
  }
}

// gather word embedding for step t into x[:, 0:E]
__global__ void embed_kernel(const int* __restrict__ captions, const float* __restrict__ emb,
                             float* __restrict__ x, int t) {
  int idx = blockIdx.x * blockDim.x + threadIdx.x; // B*E
  int b = idx >> 9, e = idx & 511;
  int tok = captions[b * TT + t];
  x[(long)b * (EE + DD) + e] = emb[(long)tok * EE + e];
}

// per-batch fused attention: score = va . tanh(att1 + a2) + bv; softmax; ctx
__global__ void attn_kernel(const float* __restrict__ att1, const float* __restrict__ a2,
                            const float* __restrict__ va, const float* __restrict__ bv,
                            const float* __restrict__ features, float* __restrict__ x,
                            float* __restrict__ att_out, int t) {
  int b = blockIdx.x, tid = threadIdx.x;
  __shared__ float a2s[HH];
  __shared__ float sc[64];
  for (int i = tid; i < HH; i += 256) a2s[i] = a2[b * HH + i];
  __syncthreads();
  int wave = tid >> 6, lane = tid & 63;
  for (int r = wave; r < RR; r += 4) {
    const float* row = att1 + ((long)b * RR + r) * HH;
    float p = 0.f;
    for (int h = lane; h < HH; h += 64) p += va[h] * tanhf(row[h] + a2s[h]);
#pragma unroll
    for (int off = 32; off > 0; off >>= 1) p += __shfl_down(p, off, 64);
    if (lane == 0) sc[r] = p + bv[0];
  }
  __syncthreads();
  if (tid < 64) {
    float v = (tid < RR) ? sc[tid] : -1e30f;
    float m = v;
#pragma unroll
    for (int off = 32; off > 0; off >>= 1) m = fmaxf(m, __shfl_xor(m, off, 64));
    float e = (tid < RR) ? expf(v - m) : 0.f;
    float s = e;
#pragma unroll
    for (int off = 32; off > 0; off >>= 1) s += __shfl_xor(s, off, 64);
    float w = e / s;
    if (tid < RR) {
      sc[tid] = w;
      att_out[((long)b * TT + t) * RR + tid] = w;
    }
  }
  __syncthreads();
  for (int d = tid; d < DD; d += 256) {
    float acc = 0.f;
#pragma unroll 7
    for (int r = 0; r < RR; ++r) acc += sc[r] * features[((long)b * RR + r) * DD + d];
    x[(long)b * (EE + DD) + EE + d] = acc;
  }
}

// LSTM pointwise + BatchNorm over batch (biased var, two-pass), one block/channel
__global__ void lstm_bn_kernel(const float* __restrict__ gates, float* __restrict__ c,
                               float* __restrict__ h, const float* __restrict__ g1,
                               const float* __restrict__ be1) {
  int ch = blockIdx.x;  // 0..511
  int b = threadIdx.x;  // 0..127
  const float* gr = gates + (long)b * 4 * HH;
  float ig = sigmoidf(gr[ch]);
  float fg = sigmoidf(gr[HH + ch]);
  float gg = tanhf(gr[2 * HH + ch]);
  float og = sigmoidf(gr[3 * HH + ch]);
  float cn = fg * c[b * HH + ch] + ig * gg;
  c[b * HH + ch] = cn;
  float hr = og * tanhf(cn);
  __shared__ float s1[128];
  s1[b] = hr;
  __syncthreads();
  for (int off = 64; off > 0; off >>= 1) {
    if (b < off) s1[b] += s1[b + off];
    __syncthreads();
  }
  float mean = s1[0] * (1.f / 128);
  __syncthreads();
  float dv = hr - mean;
  s1[b] = dv * dv;
  __syncthreads();
  for (int off = 64; off > 0; off >>= 1) {
    if (b < off) s1[b] += s1[b + off];
    __syncthreads();
  }
  float var = s1[0] * (1.f / 128);
  h[b * HH + ch] = dv * (1.f / sqrtf(var + EPSV)) * g1[ch] + be1[ch];
}

// plain BatchNorm (training stats, two-pass) over batch, one block per channel
__global__ void bn_kernel(const float* __restrict__ X, float* __restrict__ Y,
                          const float* __restrict__ g, const float* __restrict__ be, int C) {
  int ch = blockIdx.x;
  int b = threadIdx.x;
  float xv = X[b * C + ch];
  __shared__ float s1[128];
  s1[b] = xv;
  __syncthreads();
  for (int off = 64; off > 0; off >>= 1) {
    if (b < off) s1[b] += s1[b + off];
    __syncthreads();
  }
  float mean = s1[0] * (1.f / 128);
  __syncthreads();
  float dv = xv - mean;
  s1[b] = dv * dv;
  __syncthreads();
  for (int off = 64; off > 0; off >>= 1) {
    if (b < off) s1[b] += s1[b + off];
    __syncthreads();
  }
  float var = s1[0] * (1.f / 128);
  Y[b * C + ch] = dv * (1.f / sqrtf(var + EPSV)) * g[ch] + be[ch];
}

extern "C" void kernel_launch(void* const* d_in, const int* in_sizes, int n_in,
                              void* d_out, int out_size, void* d_ws, size_t ws_size,
                              hipStream_t stream) {
  const int*   captions = (const int*)d_in[0];
  const float* features = (const float*)d_in[1];
  const float* emb   = (const float*)d_in[2];
  const float* Wa    = (const float*)d_in[3];
  const float* ba    = (const float*)d_in[4];
  const float* Ua    = (const float*)d_in[5];
  const float* bu    = (const float*)d_in[6];
  const float* va    = (const float*)d_in[7];
  const float* bv    = (const float*)d_in[8];
  const float* W_ih  = (const float*)d_in[9];
  const float* b_ih  = (const float*)d_in[10];
  const float* W_hh  = (const float*)d_in[11];
  const float* b_hh  = (const float*)d_in[12];
  const float* g1    = (const float*)d_in[13];
  const float* be1   = (const float*)d_in[14];
  const float* fc_w  = (const float*)d_in[15];
  const float* fc_b  = (const float*)d_in[16];
  const float* g2    = (const float*)d_in[17];
  const float* be2   = (const float*)d_in[18];
  const float* fc2_w = (const float*)d_in[19];
  const float* fc2_b = (const float*)d_in[20];
  const float* ih_w  = (const float*)d_in[21];
  const float* ih_b  = (const float*)d_in[22];
  const float* ic_w  = (const float*)d_in[23];
  const float* ic_b  = (const float*)d_in[24];

  float* out = (float*)d_out;                 // [B,T,V]
  float* att_out = out + (long)BQ * TT * VV;  // [B,T,R]

  float* ws = (float*)d_ws;
  float* mean_f = ws;                      // B*D
  float* att1   = mean_f + BQ * DD;        // B*R*H
  float* h      = att1 + BQ * RR * HH;     // B*H
  float* c      = h + BQ * HH;             // B*H
  float* a2     = c + BQ * HH;             // B*H
  float* x      = a2 + BQ * HH;            // B*(E+D)
  float* gates  = x + BQ * (EE + DD);      // B*4H
  float* out1   = gates + BQ * 4 * HH;     // B*256
  float* out2   = out1 + BQ * 256;         // B*256

  // ---- one-time prologue ----
  mean_kernel<<<(BQ * DD + 255) / 256, 256, 0, stream>>>(features, mean_f);
  gemm_tn<<<dim3(HH / 64, BQ / 64), 256, 0, stream>>>(
      mean_f, ih_w, ih_b, h, BQ, HH, DD, HH, 0, 0);
  gemm_tn<<<dim3(HH / 64, BQ / 64), 256, 0, stream>>>(
      mean_f, ic_w, ic_b, c, BQ, HH, DD, HH, 0, 0);
  gemm_tn<<<dim3(HH / 64, (BQ * RR + 63) / 64), 256, 0, stream>>>(
      features, Wa, ba, att1, BQ * RR, HH, DD, HH, 0, 0);

  // ---- timestep loop (all enqueued; stream-ordered) ----
  for (int t = 0; t < TT; ++t) {
    gemm_tn<<<dim3(HH / 64, BQ / 64), 256, 0, stream>>>(
        h, Ua, bu, a2, BQ, HH, HH, HH, 0, 0);
    attn_kernel<<<BQ, 256, 0, stream>>>(att1, a2, va, bv, features, x, att_out, t);
    embed_kernel<<<BQ * EE / 256, 256, 0, stream>>>(captions, emb, x, t);
    gemm_tn<<<dim3(4 * HH / 64, BQ / 64), 256, 0, stream>>>(
        x, W_ih, b_ih, gates, BQ, 4 * HH, EE + DD, 4 * HH, 0, 0);
    gemm_tn<<<dim3(4 * HH / 64, BQ / 64), 256, 0, stream>>>(
        h, W_hh, b_hh, gates, BQ, 4 * HH, HH, 4 * HH, 1, 0);
    lstm_bn_kernel<<<HH, 128, 0, stream>>>(gates, c, h, g1, be1);
    gemm_tn<<<dim3(256 / 64, BQ / 64), 256, 0, stream>>>(
        h, fc_w, fc_b, out1, BQ, 256, HH, 256, 0, 1);
    bn_kernel<<<256, 128, 0, stream>>>(out1, out2, g2, be2, 256);
    gemm_tn<<<dim3((VV + 63) / 64, BQ / 64), 256, 0, stream>>>(
        out2, fc2_w, fc2_b, out + (long)t * VV, BQ, VV, 256, (long)TT * VV, 0, 0);
  }
}

// Round 3
// 2445.502 us; speedup vs baseline: 7.2271x; 7.2271x over previous
//
#include <hip/hip_runtime.h>
#include <hip/hip_bf16.h>
#include <math.h>

typedef __hip_bfloat16 bf16;
typedef short bf16x8 __attribute__((ext_vector_type(8)));
typedef float f32x4 __attribute__((ext_vector_type(4)));

#define BQ 128   // batch
#define TT 20    // timesteps
#define RR 49    // regions
#define DD 2048  // feature dim
#define EE 512   // embed dim
#define HH 512   // hidden
#define VV 10000 // vocab
#define XW 3072  // xcat width = E + D + H
constexpr float EPSV = 1e-5f;
#define APITCH 40  // LDS row pitch in bf16 elems (80B) — breaks pow2 bank stride

__device__ __forceinline__ float sigmoidf(float x) { return 1.f / (1.f + expf(-x)); }
__device__ __forceinline__ bf16 f2b(float v) { return __float2bfloat16(v); }
__device__ __forceinline__ float b2f(bf16 v) { return __bfloat162float(v); }

// ---------------- MFMA GEMM ----------------
// C[M,N] = A[M,K] @ W[N,K]^T + bias, optional relu.
// A,W bf16 K-contiguous. M must be multiple of 128 (grid.y = M/128).
// Outputs: Cf (fp32) and/or Cb (bf16) with row stride ldc; Cb2 (bf16, ldc2).
__global__ __launch_bounds__(256) void gemm_mfma(
    const bf16* __restrict__ A, const bf16* __restrict__ W,
    const float* __restrict__ bias,
    float* __restrict__ Cf, bf16* __restrict__ Cb, bf16* __restrict__ Cb2,
    long ldc, long ldc2, int N, int K, int act) {
  __shared__ __align__(16) short Alds[128 * APITCH];
  __shared__ __align__(16) short Wlds[64 * APITCH];
  int tid = threadIdx.x;
  int bm = blockIdx.y * 128, bn = blockIdx.x * 64;
  int w = tid >> 6, l = tid & 63;
  int lr = l & 15, lq = l >> 4;           // C col / k-quad
  int srow = tid >> 2, skq = (tid & 3) * 8;  // staging row / k-offset
  const bf16* pa0 = A + (long)(bm + srow) * K + skq;
  const bf16* pa1 = pa0 + (long)64 * K;
  const bf16* pw = W + (long)(bn + srow) * K + skq;
  bool wok = (bn + srow) < N;
  f32x4 acc[2][4] = {};
  uint4 ra0 = *(const uint4*)pa0;
  uint4 ra1 = *(const uint4*)pa1;
  uint4 rw = wok ? *(const uint4*)pw : make_uint4(0, 0, 0, 0);
  for (int k0 = 0; k0 < K; k0 += 32) {
    __syncthreads();
    *(uint4*)&Alds[srow * APITCH + skq] = ra0;
    *(uint4*)&Alds[(srow + 64) * APITCH + skq] = ra1;
    *(uint4*)&Wlds[srow * APITCH + skq] = rw;
    if (k0 + 32 < K) {  // prefetch next tile (overlaps barrier+MFMA)
      ra0 = *(const uint4*)(pa0 + k0 + 32);
      ra1 = *(const uint4*)(pa1 + k0 + 32);
      rw = wok ? *(const uint4*)(pw + k0 + 32) : make_uint4(0, 0, 0, 0);
    }
    __syncthreads();
    bf16x8 af[2], bfr[4];
#pragma unroll
    for (int mt = 0; mt < 2; ++mt)
      af[mt] = *(const bf16x8*)&Alds[(w * 32 + mt * 16 + lr) * APITCH + lq * 8];
#pragma unroll
    for (int nt = 0; nt < 4; ++nt)
      bfr[nt] = *(const bf16x8*)&Wlds[(nt * 16 + lr) * APITCH + lq * 8];
#pragma unroll
    for (int mt = 0; mt < 2; ++mt)
#pragma unroll
      for (int nt = 0; nt < 4; ++nt)
        acc[mt][nt] = __builtin_amdgcn_mfma_f32_16x16x32_bf16(
            af[mt], bfr[nt], acc[mt][nt], 0, 0, 0);
  }
  // epilogue: C/D layout col=lane&15, row=(lane>>4)*4+i
#pragma unroll
  for (int mt = 0; mt < 2; ++mt) {
    int gm = bm + w * 32 + mt * 16 + lq * 4;
#pragma unroll
    for (int nt = 0; nt < 4; ++nt) {
      int gn = bn + nt * 16 + lr;
      if (gn >= N) continue;
      float bv = bias ? bias[gn] : 0.f;
#pragma unroll
      for (int i = 0; i < 4; ++i) {
        float v = acc[mt][nt][i] + bv;
        if (act) v = fmaxf(v, 0.f);
        long row = gm + i;
        if (Cf) Cf[row * ldc + gn] = v;
        if (Cb) Cb[row * ldc + gn] = f2b(v);
        if (Cb2) Cb2[row * ldc2 + gn] = f2b(v);
      }
    }
  }
}

// ---------------- small kernels ----------------
// mean over R regions -> bf16 [B,D]
__global__ void mean_kernel(const float* __restrict__ feat, bf16* __restrict__ meanbf) {
  int idx = blockIdx.x * blockDim.x + threadIdx.x;
  if (idx >= BQ * DD) return;
  int b = idx / DD, d = idx - b * DD;
  const float* p = feat + (long)b * RR * DD + d;
  float s = 0.f;
  for (int r = 0; r < RR; ++r) s += p[(long)r * DD];
  meanbf[idx] = f2b(s * (1.f / RR));
}

// fp32 -> bf16, 4 elems/thread
__global__ void f2b_kernel(const float* __restrict__ src, bf16* __restrict__ dst, long n4) {
  long i = (long)blockIdx.x * blockDim.x + threadIdx.x;
  if (i >= n4) return;
  float4 v = ((const float4*)src)[i];
  bf16 o[4] = {f2b(v.x), f2b(v.y), f2b(v.z), f2b(v.w)};
  *(ushort4*)(dst + i * 4) = *(const ushort4*)o;
}

// pack [W_ih | W_hh] -> Wcat bf16 [2048][3072]
__global__ void wcat_kernel(const float* __restrict__ W_ih, const float* __restrict__ W_hh,
                            bf16* __restrict__ Wcat) {
  int n = blockIdx.y;
  int kc = (blockIdx.x * blockDim.x + threadIdx.x) * 4;  // 0..3068
  float4 v = (kc < EE + DD) ? *(const float4*)(W_ih + (long)n * (EE + DD) + kc)
                            : *(const float4*)(W_hh + (long)n * HH + (kc - EE - DD));
  bf16 o[4] = {f2b(v.x), f2b(v.y), f2b(v.z), f2b(v.w)};
  *(ushort4*)(Wcat + (long)n * XW + kc) = *(const ushort4*)o;
}

__global__ void biasc_kernel(const float* __restrict__ b_ih, const float* __restrict__ b_hh,
                             float* __restrict__ bc) {
  int i = blockIdx.x * blockDim.x + threadIdx.x;
  if (i < 4 * HH) bc[i] = b_ih[i] + b_hh[i];
}

// embedding gather for step t -> xcat[:,0:E] bf16
__global__ void embed_kernel(const int* __restrict__ cap, const float* __restrict__ emb,
                             bf16* __restrict__ xcat, int t) {
  int idx = blockIdx.x * blockDim.x + threadIdx.x;  // B*E/4
  int b = idx >> 7, e4 = (idx & 127) * 4;
  int tok = cap[b * TT + t];
  float4 v = *(const float4*)(emb + (long)tok * EE + e4);
  bf16 o[4] = {f2b(v.x), f2b(v.y), f2b(v.z), f2b(v.w)};
  *(ushort4*)(xcat + (long)b * XW + e4) = *(const ushort4*)o;
}

// fused attention: score = va.tanh(att1 + a2) + bv; softmax; ctx -> xcat bf16
__global__ __launch_bounds__(256) void attn_kernel(
    const bf16* __restrict__ att1, const float* __restrict__ a2,
    const float* __restrict__ va, const float* __restrict__ bv,
    const bf16* __restrict__ feat, bf16* __restrict__ xcat,
    float* __restrict__ att_out, int t) {
  int b = blockIdx.x, tid = threadIdx.x;
  __shared__ float a2s[HH], vas[HH];
  __shared__ float sc[64];
  for (int i = tid; i < HH; i += 256) { a2s[i] = a2[b * HH + i]; vas[i] = va[i]; }
  __syncthreads();
  int wave = tid >> 6, lane = tid & 63;
  for (int r = wave; r < RR; r += 4) {
    bf16 rv[8];
    *(uint4*)rv = *(const uint4*)(att1 + ((long)b * RR + r) * HH + lane * 8);
    float p = 0.f;
#pragma unroll
    for (int j = 0; j < 8; ++j) {
      int h = lane * 8 + j;
      p += vas[h] * tanhf(b2f(rv[j]) + a2s[h]);
    }
#pragma unroll
    for (int off = 32; off > 0; off >>= 1) p += __shfl_down(p, off, 64);
    if (lane == 0) sc[r] = p + bv[0];
  }
  __syncthreads();
  if (tid < 64) {
    float v = (tid < RR) ? sc[tid] : -1e30f;
    float m = v;
#pragma unroll
    for (int off = 32; off > 0; off >>= 1) m = fmaxf(m, __shfl_xor(m, off, 64));
    float e = (tid < RR) ? expf(v - m) : 0.f;
    float s = e;
#pragma unroll
    for (int off = 32; off > 0; off >>= 1) s += __shfl_xor(s, off, 64);
    float wgt = e / s;
    if (tid < RR) {
      sc[tid] = wgt;
      att_out[((long)b * TT + t) * RR + tid] = wgt;
    }
  }
  __syncthreads();
  // ctx: each thread owns 8 d's
  const bf16* fb = feat + (long)b * RR * DD + tid * 8;
  float accv[8] = {};
  for (int r = 0; r < RR; ++r) {
    bf16 fv[8];
    *(uint4*)fv = *(const uint4*)(fb + (long)r * DD);
    float wr = sc[r];
#pragma unroll
    for (int j = 0; j < 8; ++j) accv[j] += wr * b2f(fv[j]);
  }
  bf16 ov[8];
#pragma unroll
  for (int j = 0; j < 8; ++j) ov[j] = f2b(accv[j]);
  *(uint4*)(xcat + (long)b * XW + EE + tid * 8) = *(const uint4*)ov;
}

// LSTM pointwise + BN1 (biased var, two-pass); writes h (bf16) twice
__global__ void lstm_bn_kernel(const float* __restrict__ gates, float* __restrict__ c,
                               bf16* __restrict__ hbf, bf16* __restrict__ xcat,
                               const float* __restrict__ g1, const float* __restrict__ be1) {
  int ch = blockIdx.x;  // 0..511
  int b = threadIdx.x;  // 0..127
  const float* gr = gates + (long)b * 4 * HH;
  float ig = sigmoidf(gr[ch]);
  float fg = sigmoidf(gr[HH + ch]);
  float gg = tanhf(gr[2 * HH + ch]);
  float og = sigmoidf(gr[3 * HH + ch]);
  float cn = fg * c[b * HH + ch] + ig * gg;
  c[b * HH + ch] = cn;
  float hr = og * tanhf(cn);
  __shared__ float s1[128];
  s1[b] = hr;
  __syncthreads();
  for (int off = 64; off > 0; off >>= 1) {
    if (b < off) s1[b] += s1[b + off];
    __syncthreads();
  }
  float mean = s1[0] * (1.f / 128);
  __syncthreads();
  float dv = hr - mean;
  s1[b] = dv * dv;
  __syncthreads();
  for (int off = 64; off > 0; off >>= 1) {
    if (b < off) s1[b] += s1[b + off];
    __syncthreads();
  }
  float var = s1[0] * (1.f / 128);
  float res = dv * (1.f / sqrtf(var + EPSV)) * g1[ch] + be1[ch];
  hbf[b * HH + ch] = f2b(res);
  xcat[(long)b * XW + EE + DD + ch] = f2b(res);
}

// BN2 (training stats, two-pass) -> bf16
__global__ void bn_kernel(const float* __restrict__ X, bf16* __restrict__ Y,
                          const float* __restrict__ g, const float* __restrict__ be, int C) {
  int ch = blockIdx.x;
  int b = threadIdx.x;
  float xv = X[b * C + ch];
  __shared__ float s1[128];
  s1[b] = xv;
  __syncthreads();
  for (int off = 64; off > 0; off >>= 1) {
    if (b < off) s1[b] += s1[b + off];
    __syncthreads();
  }
  float mean = s1[0] * (1.f / 128);
  __syncthreads();
  float dv = xv - mean;
  s1[b] = dv * dv;
  __syncthreads();
  for (int off = 64; off > 0; off >>= 1) {
    if (b < off) s1[b] += s1[b + off];
    __syncthreads();
  }
  float var = s1[0] * (1.f / 128);
  Y[b * C + ch] = f2b(dv * (1.f / sqrtf(var + EPSV)) * g[ch] + be[ch]);
}

extern "C" void kernel_launch(void* const* d_in, const int* in_sizes, int n_in,
                              void* d_out, int out_size, void* d_ws, size_t ws_size,
                              hipStream_t stream) {
  const int* captions  = (const int*)d_in[0];
  const float* features = (const float*)d_in[1];
  const float* emb   = (const float*)d_in[2];
  const float* Wa    = (const float*)d_in[3];
  const float* ba    = (const float*)d_in[4];
  const float* Ua    = (const float*)d_in[5];
  const float* bu    = (const float*)d_in[6];
  const float* va    = (const float*)d_in[7];
  const float* bv    = (const float*)d_in[8];
  const float* W_ih  = (const float*)d_in[9];
  const float* b_ih  = (const float*)d_in[10];
  const float* W_hh  = (const float*)d_in[11];
  const float* b_hh  = (const float*)d_in[12];
  const float* g1    = (const float*)d_in[13];
  const float* be1   = (const float*)d_in[14];
  const float* fc_w  = (const float*)d_in[15];
  const float* fc_b  = (const float*)d_in[16];
  const float* g2    = (const float*)d_in[17];
  const float* be2   = (const float*)d_in[18];
  const float* fc2_w = (const float*)d_in[19];
  const float* fc2_b = (const float*)d_in[20];
  const float* ih_w  = (const float*)d_in[21];
  const float* ih_b  = (const float*)d_in[22];
  const float* ic_w  = (const float*)d_in[23];
  const float* ic_b  = (const float*)d_in[24];

  float* out = (float*)d_out;                 // [B,T,V]
  float* att_out = out + (long)BQ * TT * VV;  // [B,T,R]

  char* p = (char*)d_ws;
  auto alloc = [&](size_t bytes) { char* r = p; p += (bytes + 255) & ~255ULL; return r; };
  bf16* featbf = (bf16*)alloc((size_t)BQ * RR * DD * 2);
  bf16* meanbf = (bf16*)alloc((size_t)BQ * DD * 2);
  bf16* Wcat   = (bf16*)alloc((size_t)4 * HH * XW * 2);
  bf16* Wabf   = (bf16*)alloc((size_t)HH * DD * 2);
  bf16* Uabf   = (bf16*)alloc((size_t)HH * HH * 2);
  bf16* fcwbf  = (bf16*)alloc((size_t)256 * HH * 2);
  bf16* fc2wbf = (bf16*)alloc((size_t)VV * 256 * 2);
  bf16* ihwbf  = (bf16*)alloc((size_t)HH * DD * 2);
  bf16* icwbf  = (bf16*)alloc((size_t)HH * DD * 2);
  bf16* att1bf = (bf16*)alloc((size_t)BQ * RR * HH * 2);
  bf16* xcat   = (bf16*)alloc((size_t)BQ * XW * 2);
  bf16* hbf    = (bf16*)alloc((size_t)BQ * HH * 2);
  bf16* out2bf = (bf16*)alloc((size_t)BQ * 256 * 2);
  float* biasc = (float*)alloc((size_t)4 * HH * 4);
  float* c     = (float*)alloc((size_t)BQ * HH * 4);
  float* a2    = (float*)alloc((size_t)BQ * HH * 4);
  float* gates = (float*)alloc((size_t)BQ * 4 * HH * 4);
  float* out1  = (float*)alloc((size_t)BQ * 256 * 4);

  // ---- prologue: dtype conversion / packing ----
  f2b_kernel<<<(BQ * RR * DD / 4 + 255) / 256, 256, 0, stream>>>(features, featbf, BQ * RR * DD / 4);
  f2b_kernel<<<(HH * DD / 4 + 255) / 256, 256, 0, stream>>>(Wa, Wabf, HH * DD / 4);
  f2b_kernel<<<(HH * HH / 4 + 255) / 256, 256, 0, stream>>>(Ua, Uabf, HH * HH / 4);
  f2b_kernel<<<(256 * HH / 4 + 255) / 256, 256, 0, stream>>>(fc_w, fcwbf, 256 * HH / 4);
  f2b_kernel<<<(VV * 256 / 4 + 255) / 256, 256, 0, stream>>>(fc2_w, fc2wbf, VV * 256 / 4);
  f2b_kernel<<<(HH * DD / 4 + 255) / 256, 256, 0, stream>>>(ih_w, ihwbf, HH * DD / 4);
  f2b_kernel<<<(HH * DD / 4 + 255) / 256, 256, 0, stream>>>(ic_w, icwbf, HH * DD / 4);
  wcat_kernel<<<dim3(XW / 4 / 256, 4 * HH), 256, 0, stream>>>(W_ih, W_hh, Wcat);
  biasc_kernel<<<(4 * HH + 255) / 256, 256, 0, stream>>>(b_ih, b_hh, biasc);
  mean_kernel<<<(BQ * DD + 255) / 256, 256, 0, stream>>>(features, meanbf);

  // h0 -> hbf + xcat h-slice; c0 -> c (fp32)
  gemm_mfma<<<dim3(HH / 64, 1), 256, 0, stream>>>(
      meanbf, ihwbf, ih_b, nullptr, hbf, xcat + EE + DD, HH, XW, HH, DD, 0);
  gemm_mfma<<<dim3(HH / 64, 1), 256, 0, stream>>>(
      meanbf, icwbf, ic_b, c, nullptr, nullptr, HH, 0, HH, DD, 0);
  // att1 = features @ Wa^T + ba  (bf16 out)
  gemm_mfma<<<dim3(HH / 64, BQ * RR / 128), 256, 0, stream>>>(
      featbf, Wabf, ba, nullptr, att1bf, nullptr, HH, 0, HH, DD, 0);

  // ---- timestep loop ----
  for (int t = 0; t < TT; ++t) {
    gemm_mfma<<<dim3(HH / 64, 1), 256, 0, stream>>>(
        hbf, Uabf, bu, a2, nullptr, nullptr, HH, 0, HH, HH, 0);
    attn_kernel<<<BQ, 256, 0, stream>>>(att1bf, a2, va, bv, featbf, xcat, att_out, t);
    embed_kernel<<<BQ * EE / 4 / 256, 256, 0, stream>>>(captions, emb, xcat, t);
    gemm_mfma<<<dim3(4 * HH / 64, 1), 256, 0, stream>>>(
        xcat, Wcat, biasc, gates, nullptr, nullptr, 4 * HH, 0, 4 * HH, XW, 0);
    lstm_bn_kernel<<<HH, 128, 0, stream>>>(gates, c, hbf, xcat, g1, be1);
    gemm_mfma<<<dim3(256 / 64, 1), 256, 0, stream>>>(
        hbf, fcwbf, fc_b, out1, nullptr, nullptr, 256, 0, 256, HH, 1);
    bn_kernel<<<256, 128, 0, stream>>>(out1, out2bf, g2, be2, 256);
    gemm_mfma<<<dim3((VV + 63) / 64, 1), 256, 0, stream>>>(
        out2bf, fc2wbf, fc2_b, out + (long)t * VV, nullptr, nullptr,
        (long)TT * VV, 0, VV, 256, 0);
  }
}